// Round 2
// baseline (655.363 us; speedup 1.0000x reference)
//
#include <hip/hip_runtime.h>

// Problem constants (match reference)
constexpr int   S_     = 16;
constexpr int   N_     = 8192;
constexpr int   NSRC   = 10000;
constexpr int   MINDST = 10000;
constexpr float TDMAX  = 5000.0f;

// Grid shapes
constexpr int SURV_BLOCKS = (S_ * N_) / 4;   // 32768 blocks, 1 wave per (s,i) row
constexpr int LAM_BLOCKS  = N_ / 4;          // 2048 blocks... wait: 1 wave per i -> N_/4 waves? no:
// lambda kernel: 1 wave per event i -> N_ waves -> N_/4 = 2048 blocks

__device__ __forceinline__ float wave_reduce_sum(float v) {
#pragma unroll
    for (int off = 32; off > 0; off >>= 1)
        v += __shfl_xor(v, off, 64);
    return v;
}

// psi * (log1p(exp(-g_psi)) + g_psi), g = dot + b + alpha*exp(-w_t * td/TDMAX)
__device__ __forceinline__ float hawkes(float gdot, float td,
                                        float b, float psi, float alpha, float wt) {
    float g  = gdot + b + alpha * expf(-wt * (td * (1.0f / TDMAX)));
    float gp = g / (psi + 1e-7f);
    gp = fminf(fmaxf(gp, -75.0f), 75.0f);
    return psi * (log1pf(expf(-gp)) + gp);
}

// Survival kernel: one wave per row-pair q = s*N + i. No atomics: block partial -> ws_s[blockIdx].
__global__ __launch_bounds__(256) void surv_kernel(
    const int*   __restrict__ src,
    const int*   __restrict__ dst,
    const int*   __restrict__ assoc,
    const float* __restrict__ last_update,
    const float* __restrict__ cur_time,
    const float* __restrict__ last_time_pos,
    const float* __restrict__ u_non,           // (S*N, 256)
    const float* __restrict__ v_non,           // (S*N, 256)
    const float* __restrict__ td_step,         // (S*N,) flat
    const float* __restrict__ W,               // (512,)
    const float* __restrict__ b_p,
    const float* __restrict__ psi_p,
    const float* __restrict__ alpha_p,
    const float* __restrict__ wt_p,
    float* __restrict__ ws_s)                  // [SURV_BLOCKS]
{
    const int wave = threadIdx.x >> 6;
    const int lane = threadIdx.x & 63;
    const int q    = (blockIdx.x << 2) + wave;   // row index in [0, S*N)
    const int i    = q & (N_ - 1);               // N is a power of two

    const float4* __restrict__ W4 = (const float4*)W;
    const float4 wu = W4[lane];
    const float4 wv = W4[64 + lane];

    // Issue the big row loads FIRST (independent of the scalar chain)
    const float4* __restrict__ U4 = (const float4*)u_non;
    const float4* __restrict__ V4 = (const float4*)v_non;
    const float4 uu = U4[(size_t)q * 64 + lane];
    const float4 vv = V4[(size_t)q * 64 + lane];
    const float ts = td_step[q];

    // Per-event scalars (wave-uniform, L2-resident after first touch)
    const int si = src[i];
    const int di = dst[i];
    const int as = assoc[si];
    const int ad = assoc[di];
    const float lum   = fmaxf(last_update[as], last_update[ad]);
    const float td_uv = cur_time[i] - fmaxf(lum, last_time_pos[i]);

    float d = uu.x * wu.x + uu.y * wu.y + uu.z * wu.z + uu.w * wu.w
            + vv.x * wv.x + vv.y * wv.y + vv.z * wv.z + vv.w * wv.w;
    d = wave_reduce_sum(d);

    const float b0    = b_p[0];
    const float psi   = psi_p[0];
    const float alpha = alpha_p[0];
    const float wt    = wt_p[0];
    const float contrib = hawkes(d, ts * td_uv, b0, psi, alpha, wt)
                        * td_uv * (1.0f / S_);

    __shared__ float sh[4];
    if (lane == 0) sh[wave] = contrib;
    __syncthreads();
    if (threadIdx.x == 0)
        ws_s[blockIdx.x] = sh[0] + sh[1] + sh[2] + sh[3];
}

// Lambda + accu kernel: one wave per event i. Partials -> ws_l[b], ws_a[b].
__global__ __launch_bounds__(256) void lambda_kernel(
    const float* __restrict__ emb,             // (20000, 256)
    const int*   __restrict__ assoc,
    const int*   __restrict__ src,
    const int*   __restrict__ dst,
    const float* __restrict__ last_update,
    const float* __restrict__ cur_time,
    const float* __restrict__ last_time_pos,
    const float* __restrict__ accu,            // (NSRC, NSRC)
    const float* __restrict__ W,
    const float* __restrict__ b_p,
    const float* __restrict__ psi_p,
    const float* __restrict__ alpha_p,
    const float* __restrict__ wt_p,
    float* __restrict__ ws_l,                  // [LAM_BLOCKS]
    float* __restrict__ ws_a)                  // [LAM_BLOCKS]
{
    const int wave = threadIdx.x >> 6;
    const int lane = threadIdx.x & 63;
    const int i    = (blockIdx.x << 2) + wave;

    const float4* __restrict__ W4 = (const float4*)W;
    const float4 wu = W4[lane];
    const float4 wv = W4[64 + lane];

    const int si = src[i];
    const int di = dst[i];
    const int as = assoc[si];
    const int ad = assoc[di];
    const float lus = last_update[as];
    const float lud = last_update[ad];
    const float lum = fmaxf(lus, lud);
    const float ltp = last_time_pos[i];
    const float td_uv = cur_time[i] - fmaxf(lum, ltp);

    const float4* __restrict__ Z4 = (const float4*)emb;
    const float4 zs = Z4[(size_t)as * 64 + lane];
    const float4 zd = Z4[(size_t)ad * 64 + lane];
    float d = zs.x * wu.x + zs.y * wu.y + zs.z * wu.z + zs.w * wu.w
            + zd.x * wv.x + zd.y * wv.y + zd.z * wv.z + zd.w * wv.w;
    d = wave_reduce_sum(d);

    const float lam = hawkes(d, td_uv, b_p[0], psi_p[0], alpha_p[0], wt_p[0]);
    const float part_l = -logf(lam + 1e-7f);

    float part_a = accu[(size_t)si * NSRC + (di - MINDST)];
    part_a = (ltp >= lum) ? part_a : 0.0f;

    __shared__ float shl[4], sha[4];
    if (lane == 0) { shl[wave] = part_l; sha[wave] = part_a; }
    __syncthreads();
    if (threadIdx.x == 0) {
        ws_l[blockIdx.x] = shl[0] + shl[1] + shl[2] + shl[3];
        ws_a[blockIdx.x] = sha[0] + sha[1] + sha[2] + sha[3];
    }
}

// Final reduction: one block sums all partials, writes out[0], out[1] directly.
__global__ __launch_bounds__(256) void finalize_kernel(
    const float* __restrict__ ws_s,   // [SURV_BLOCKS]
    const float* __restrict__ ws_l,   // [LAM_BLOCKS]
    const float* __restrict__ ws_a,   // [LAM_BLOCKS]
    float* __restrict__ out)
{
    float sS = 0.0f, sL = 0.0f;
    for (int j = threadIdx.x; j < SURV_BLOCKS; j += 256) sS += ws_s[j];
    for (int j = threadIdx.x; j < LAM_BLOCKS; j += 256) {
        sS += ws_a[j];
        sL += ws_l[j];
    }
    sS = wave_reduce_sum(sS);
    sL = wave_reduce_sum(sL);

    __shared__ float shS[4], shL[4];
    const int wave = threadIdx.x >> 6;
    const int lane = threadIdx.x & 63;
    if (lane == 0) { shS[wave] = sS; shL[wave] = sL; }
    __syncthreads();
    if (threadIdx.x == 0) {
        out[0] = (shL[0] + shL[1] + shL[2] + shL[3]) * (1.0f / N_);
        out[1] = (shS[0] + shS[1] + shS[2] + shS[3]) * (1.0f / N_);
    }
}

extern "C" void kernel_launch(void* const* d_in, const int* in_sizes, int n_in,
                              void* d_out, int out_size, void* d_ws, size_t ws_size,
                              hipStream_t stream) {
    const float* emb           = (const float*)d_in[0];
    const int*   assoc         = (const int*)  d_in[1];
    const int*   src           = (const int*)  d_in[2];
    const int*   dst           = (const int*)  d_in[3];
    const float* last_update   = (const float*)d_in[4];
    const float* cur_time      = (const float*)d_in[5];
    const float* u_non         = (const float*)d_in[6];
    const float* v_non         = (const float*)d_in[7];
    const float* last_time_pos = (const float*)d_in[8];
    const float* td_step       = (const float*)d_in[9];
    const float* accu          = (const float*)d_in[10];
    const float* W             = (const float*)d_in[11];
    const float* b_p           = (const float*)d_in[12];
    const float* psi_p         = (const float*)d_in[13];
    const float* alpha_p       = (const float*)d_in[14];
    const float* wt_p          = (const float*)d_in[15];
    float* out = (float*)d_out;

    float* ws_s = (float*)d_ws;              // [SURV_BLOCKS]
    float* ws_l = ws_s + SURV_BLOCKS;        // [LAM_BLOCKS]
    float* ws_a = ws_l + LAM_BLOCKS;         // [LAM_BLOCKS]

    surv_kernel<<<SURV_BLOCKS, 256, 0, stream>>>(
        src, dst, assoc, last_update, cur_time, last_time_pos,
        u_non, v_non, td_step, W, b_p, psi_p, alpha_p, wt_p, ws_s);

    lambda_kernel<<<LAM_BLOCKS, 256, 0, stream>>>(
        emb, assoc, src, dst, last_update, cur_time, last_time_pos,
        accu, W, b_p, psi_p, alpha_p, wt_p, ws_l, ws_a);

    finalize_kernel<<<1, 256, 0, stream>>>(ws_s, ws_l, ws_a, out);
}

// Round 3
// 644.975 us; speedup vs baseline: 1.0161x; 1.0161x over previous
//
#include <hip/hip_runtime.h>

// Problem constants (match reference)
constexpr int   S_     = 16;
constexpr int   N_     = 8192;
constexpr int   NSRC   = 10000;
constexpr int   MINDST = 10000;
constexpr float TDMAX  = 5000.0f;

// One wave handles rows q = w and q + TOTAL_WAVES (same event i, steps s and s+8)
constexpr int TOTAL_WAVES = S_ * N_ / 2;       // 65536
constexpr int MAIN_BLOCKS = TOTAL_WAVES / 4;   // 16384 blocks, 4 waves each

__device__ __forceinline__ float wave_reduce_sum(float v) {
#pragma unroll
    for (int off = 32; off > 0; off >>= 1)
        v += __shfl_xor(v, off, 64);
    return v;
}

// psi * (log1p(exp(-g_psi)) + g_psi), g = dot + b + alpha*exp(-w_t * td/TDMAX)
__device__ __forceinline__ float hawkes(float gdot, float td,
                                        float b, float psi, float alpha, float wt) {
    float g  = gdot + b + alpha * expf(-wt * (td * (1.0f / TDMAX)));
    float gp = g / (psi + 1e-7f);
    gp = fminf(fmaxf(gp, -75.0f), 75.0f);
    return psi * (log1pf(expf(-gp)) + gp);
}

// Fused kernel: survival rows (2 per wave) + lambda/accu (waves with w < N_).
__global__ __launch_bounds__(256) void fused_kernel(
    const float* __restrict__ emb,             // (20000, 256)
    const int*   __restrict__ assoc,
    const int*   __restrict__ src,
    const int*   __restrict__ dst,
    const float* __restrict__ last_update,
    const float* __restrict__ cur_time,
    const float* __restrict__ last_time_pos,
    const float* __restrict__ u_non,           // (S*N, 256)
    const float* __restrict__ v_non,           // (S*N, 256)
    const float* __restrict__ td_step,         // (S*N,) flat, row-major (S,N)
    const float* __restrict__ accu,            // (NSRC, NSRC)
    const float* __restrict__ W,               // (512,)
    const float* __restrict__ b_p,
    const float* __restrict__ psi_p,
    const float* __restrict__ alpha_p,
    const float* __restrict__ wt_p,
    float* __restrict__ ws_s,                  // [MAIN_BLOCKS] surv+accu partials
    float* __restrict__ ws_l)                  // [MAIN_BLOCKS] lambda partials
{
    const int wave = threadIdx.x >> 6;
    const int lane = threadIdx.x & 63;
    const int w    = (blockIdx.x << 2) + wave;   // global wave in [0, TOTAL_WAVES)
    const int q0   = w;                          // row for step s = w >> 13
    const int q1   = w + TOTAL_WAVES;            // row for step s+8 (same event i)
    const int i    = w & (N_ - 1);               // shared event index

    // Big streaming loads first — 4 independent float4 loads in flight
    const float4* __restrict__ U4 = (const float4*)u_non;
    const float4* __restrict__ V4 = (const float4*)v_non;
    const float4 u0 = U4[(size_t)q0 * 64 + lane];
    const float4 v0 = V4[(size_t)q0 * 64 + lane];
    const float4 u1 = U4[(size_t)q1 * 64 + lane];
    const float4 v1 = V4[(size_t)q1 * 64 + lane];
    const float ts0 = td_step[q0];
    const float ts1 = td_step[q1];

    const float4* __restrict__ W4 = (const float4*)W;
    const float4 wu = W4[lane];
    const float4 wv = W4[64 + lane];

    // Per-event scalars (wave-uniform addresses; L2-resident)
    const int si = src[i];
    const int di = dst[i];
    const int as = assoc[si];
    const int ad = assoc[di];
    const float lum   = fmaxf(last_update[as], last_update[ad]);
    const float ltp   = last_time_pos[i];
    const float td_uv = cur_time[i] - fmaxf(lum, ltp);

    const float b0    = b_p[0];
    const float psi   = psi_p[0];
    const float alpha = alpha_p[0];
    const float wt    = wt_p[0];

    float d0 = u0.x * wu.x + u0.y * wu.y + u0.z * wu.z + u0.w * wu.w
             + v0.x * wv.x + v0.y * wv.y + v0.z * wv.z + v0.w * wv.w;
    float d1 = u1.x * wu.x + u1.y * wu.y + u1.z * wu.z + u1.w * wu.w
             + v1.x * wv.x + v1.y * wv.y + v1.z * wv.z + v1.w * wv.w;
    d0 = wave_reduce_sum(d0);
    d1 = wave_reduce_sum(d1);

    float contrib = (hawkes(d0, ts0 * td_uv, b0, psi, alpha, wt) +
                     hawkes(d1, ts1 * td_uv, b0, psi, alpha, wt))
                  * td_uv * (1.0f / S_);
    float part_l = 0.0f;

    if (w < N_) {   // this wave also owns event i = w: lambda + accu terms
        const float4* __restrict__ Z4 = (const float4*)emb;
        const float4 zs = Z4[(size_t)as * 64 + lane];
        const float4 zd = Z4[(size_t)ad * 64 + lane];
        float d = zs.x * wu.x + zs.y * wu.y + zs.z * wu.z + zs.w * wu.w
                + zd.x * wv.x + zd.y * wv.y + zd.z * wv.z + zd.w * wv.w;
        d = wave_reduce_sum(d);
        const float lam = hawkes(d, td_uv, b0, psi, alpha, wt);
        part_l = -logf(lam + 1e-7f);
        if (ltp >= lum)
            contrib += accu[(size_t)si * NSRC + (di - MINDST)];
    }

    __shared__ float sh_s[4], sh_l[4];
    if (lane == 0) { sh_s[wave] = contrib; sh_l[wave] = part_l; }
    __syncthreads();
    if (threadIdx.x == 0) {
        ws_s[blockIdx.x] = sh_s[0] + sh_s[1] + sh_s[2] + sh_s[3];
        ws_l[blockIdx.x] = sh_l[0] + sh_l[1] + sh_l[2] + sh_l[3];
    }
}

// Final reduction: one block sums all partials, writes both outputs.
__global__ __launch_bounds__(256) void finalize_kernel(
    const float* __restrict__ ws_s,
    const float* __restrict__ ws_l,
    float* __restrict__ out)
{
    float sS = 0.0f, sL = 0.0f;
    for (int j = threadIdx.x; j < MAIN_BLOCKS; j += 256) {
        sS += ws_s[j];
        sL += ws_l[j];
    }
    sS = wave_reduce_sum(sS);
    sL = wave_reduce_sum(sL);

    __shared__ float shS[4], shL[4];
    const int wave = threadIdx.x >> 6;
    const int lane = threadIdx.x & 63;
    if (lane == 0) { shS[wave] = sS; shL[wave] = sL; }
    __syncthreads();
    if (threadIdx.x == 0) {
        out[0] = (shL[0] + shL[1] + shL[2] + shL[3]) * (1.0f / N_);
        out[1] = (shS[0] + shS[1] + shS[2] + shS[3]) * (1.0f / N_);
    }
}

extern "C" void kernel_launch(void* const* d_in, const int* in_sizes, int n_in,
                              void* d_out, int out_size, void* d_ws, size_t ws_size,
                              hipStream_t stream) {
    const float* emb           = (const float*)d_in[0];
    const int*   assoc         = (const int*)  d_in[1];
    const int*   src           = (const int*)  d_in[2];
    const int*   dst           = (const int*)  d_in[3];
    const float* last_update   = (const float*)d_in[4];
    const float* cur_time      = (const float*)d_in[5];
    const float* u_non         = (const float*)d_in[6];
    const float* v_non         = (const float*)d_in[7];
    const float* last_time_pos = (const float*)d_in[8];
    const float* td_step       = (const float*)d_in[9];
    const float* accu          = (const float*)d_in[10];
    const float* W             = (const float*)d_in[11];
    const float* b_p           = (const float*)d_in[12];
    const float* psi_p         = (const float*)d_in[13];
    const float* alpha_p       = (const float*)d_in[14];
    const float* wt_p          = (const float*)d_in[15];
    float* out = (float*)d_out;

    float* ws_s = (float*)d_ws;              // [MAIN_BLOCKS]
    float* ws_l = ws_s + MAIN_BLOCKS;        // [MAIN_BLOCKS]

    fused_kernel<<<MAIN_BLOCKS, 256, 0, stream>>>(
        emb, assoc, src, dst, last_update, cur_time, last_time_pos,
        u_non, v_non, td_step, accu, W, b_p, psi_p, alpha_p, wt_p,
        ws_s, ws_l);

    finalize_kernel<<<1, 256, 0, stream>>>(ws_s, ws_l, out);
}